// Round 13
// baseline (188.335 us; speedup 1.0000x reference)
//
#include <hip/hip_runtime.h>
#include <math.h>

#define NT 1024
#define EDGES 2048
#define SENT 0xFFFF

// ---------------- per-subgraph fused pipeline ----------------
struct SmemA {
  float xbuf[256 * 128];           // swizzled node features (128 KB)
  unsigned short rc[EDGES];        // (row<<8)|col ; SENT = dropped
  float ewl[EDGES];                // current edge weights
  unsigned short csr_row[EDGES];   // CSR: source row per slot
  float csr_coef[EDGES];           // CSR: dis[row]*ew per slot (aliased: leafbuf)
  float degs[256];                 // (aliased: hGacc at end)
  float diss[256];
  int   csr_off[257];
  int   csr_cnt[256];              // counts / scan input / rank accumulator
  float hsv[256];                  // score-gcn h
  float scorev[256];
  float vals[128];
  short perm[128];
  signed char newid[256];
};

// xbuf layout: row-major 128 floats/row, float4 chunks XOR-swizzled by row&7.
__device__ __forceinline__ float4* xvec(float* xb, int row, int c4) {
  return reinterpret_cast<float4*>(xb + (row << 7) + ((c4 ^ (row & 7)) << 2));
}
__device__ __forceinline__ int xidx(int row, int col) {
  return (row << 7) + ((((col >> 2) ^ (row & 7)) << 2) | (col & 3));
}

template<int NN, int K, bool FIRST, bool REMAP>
__device__ __forceinline__ void run_stage(
    SmemA& sm,
    const float* __restrict__ xg,        // stage1: global x (else nullptr)
    const int* __restrict__ eic,         // stage1: global edge index
    const float* __restrict__ ewc,       // stage1: global edge weights
    const float* __restrict__ W,         // 128x128 row-major [k][f]
    const float* __restrict__ b,         // 128
    const float* __restrict__ Wp,        // 128
    const float* __restrict__ bp,        // 1
    float& lmax, float& lmean)           // register outputs (tid<128)
{
  constexpr int NPT  = NN / 64;          // rows per lane (4/2/1)
  constexpr int Q    = NN / 64;          // scan items per lane
  constexpr int SEG  = NT / NN;          // rank segments per node
  constexpr int LEN  = NN / SEG;         // rank items per segment
  constexpr int LOG  = (NN == 256) ? 8 : (NN == 128 ? 7 : 6);
  const int tid  = threadIdx.x;
  const int lane = tid & 63;
  const int fbase = __builtin_amdgcn_readfirstlane((tid >> 6) << 3);
  const int c4b   = fbase >> 2;

  // ---- stage1 only: stage x + edges, build deg/counts ----
  if (FIRST) {
    if (tid < NN) { sm.degs[tid] = 1.0f; sm.csr_cnt[tid] = 0; }
    __syncthreads();
    const float4* xg4 = reinterpret_cast<const float4*>(xg);
    for (int i = tid; i < 256 * 32; i += NT) {
      const float4 v = xg4[i];
      *xvec(sm.xbuf, i >> 5, i & 31) = v;
    }
    for (int e = tid; e < EDGES; e += NT) {
      const int row = eic[e], col = eic[EDGES + e];
      const float w = ewc[e];
      sm.rc[e]  = (unsigned short)((row << 8) | col);
      sm.ewl[e] = w;
      atomicAdd(&sm.degs[col], w);
      atomicAdd(&sm.csr_cnt[col], 1);
    }
    __syncthreads();
  }

  // ---- diss + one-wave shuffle scan of counts -> csr_off ----
  if (tid < NN) sm.diss[tid] = rsqrtf(sm.degs[tid]);
  if (tid < 64) {
    int c[Q], pre[Q];
    int tot = 0;
#pragma unroll
    for (int i = 0; i < Q; i++) { c[i] = sm.csr_cnt[tid * Q + i]; pre[i] = tot; tot += c[i]; }
    int inc = tot;
#pragma unroll
    for (int d = 1; d < 64; d <<= 1) {
      const int o = __shfl_up(inc, d, 64);
      if (tid >= d) inc += o;
    }
    const int base = inc - tot;
    if (tid == 0) sm.csr_off[0] = 0;
#pragma unroll
    for (int i = 0; i < Q; i++) {
      sm.csr_off[tid * Q + i + 1] = base + pre[i] + c[i];
      sm.csr_cnt[tid * Q + i] = 0;
    }
  }
  __syncthreads();

  // ---- CSR fill; zero hsv + scorev here ----
  if (tid < NN) { sm.hsv[tid] = 0.0f; sm.scorev[tid] = 0.0f; }
  for (int e = tid; e < EDGES; e += NT) {
    const unsigned short r = sm.rc[e];
    if (FIRST || r != SENT) {
      const int row = r >> 8, col = r & 255;
      const int p = atomicAdd(&sm.csr_cnt[col], 1);
      const int s = sm.csr_off[col] + p;
      sm.csr_row[s]  = (unsigned short)row;
      sm.csr_coef[s] = sm.diss[row] * sm.ewl[e];
    }
  }
  __syncthreads();

  // ---- matmul: h = x @ W. Lane owns rows lane+64i; wave owns 8 cols. ----
  float acc[NPT][8];
#pragma unroll
  for (int i = 0; i < NPT; i++)
#pragma unroll
    for (int j = 0; j < 8; j++) acc[i][j] = 0.0f;

#pragma unroll 4
  for (int k4 = 0; k4 < 32; k4++) {
    float4 xv[NPT];
#pragma unroll
    for (int i = 0; i < NPT; i++) xv[i] = *xvec(sm.xbuf, lane + (i << 6), k4);
#pragma unroll
    for (int kk = 0; kk < 4; kk++) {
      const float* wr = W + (((k4 << 2) + kk) << 7) + fbase;
      const float4 wa = *reinterpret_cast<const float4*>(wr);
      const float4 wb = *reinterpret_cast<const float4*>(wr + 4);
      const float wv[8] = {wa.x, wa.y, wa.z, wa.w, wb.x, wb.y, wb.z, wb.w};
#pragma unroll
      for (int i = 0; i < NPT; i++) {
        const float xs = (kk == 0) ? xv[i].x : (kk == 1) ? xv[i].y : (kk == 2) ? xv[i].z : xv[i].w;
#pragma unroll
        for (int j = 0; j < 8; j++) acc[i][j] = fmaf(xs, wv[j], acc[i][j]);
      }
    }
  }
  __syncthreads();                 // all x reads done before overwrite

  // ---- write h to xbuf ----
#pragma unroll
  for (int i = 0; i < NPT; i++) {
    const int v = lane + (i << 6);
    *xvec(sm.xbuf, v, c4b)     = make_float4(acc[i][0], acc[i][1], acc[i][2], acc[i][3]);
    *xvec(sm.xbuf, v, c4b + 1) = make_float4(acc[i][4], acc[i][5], acc[i][6], acc[i][7]);
  }
  __syncthreads();

  // ---- agg (depth-1 prefetch) + folded epilogue + hsv partials ----
  {
    const float4 ba = *reinterpret_cast<const float4*>(b + fbase);
    const float4 bb = *reinterpret_cast<const float4*>(b + fbase + 4);
    const float bv[8] = {ba.x, ba.y, ba.z, ba.w, bb.x, bb.y, bb.z, bb.w};
    const float4 wa = *reinterpret_cast<const float4*>(Wp + fbase);
    const float4 wb = *reinterpret_cast<const float4*>(Wp + fbase + 4);
    const float wv[8] = {wa.x, wa.y, wa.z, wa.w, wb.x, wb.y, wb.z, wb.w};
#pragma unroll
    for (int i = 0; i < NPT; i++) {
      const int v = lane + (i << 6);
      const int beg = sm.csr_off[v], end = sm.csr_off[v + 1];
      float ag[8] = {0.f, 0.f, 0.f, 0.f, 0.f, 0.f, 0.f, 0.f};
      float4 plo = make_float4(0.f, 0.f, 0.f, 0.f), phi = plo;
      float cf_nxt = 0.0f;
      if (beg < end) {
        const int r0 = sm.csr_row[beg];
        cf_nxt = sm.csr_coef[beg];
        plo = *xvec(sm.xbuf, r0, c4b);
        phi = *xvec(sm.xbuf, r0, c4b + 1);
      }
      for (int s = beg; s < end; ++s) {
        const float4 lo = plo, hi = phi;
        const float cf = cf_nxt;
        if (s + 1 < end) {
          const int rn = sm.csr_row[s + 1];
          cf_nxt = sm.csr_coef[s + 1];
          plo = *xvec(sm.xbuf, rn, c4b);
          phi = *xvec(sm.xbuf, rn, c4b + 1);
        }
        ag[0] = fmaf(cf, lo.x, ag[0]); ag[1] = fmaf(cf, lo.y, ag[1]);
        ag[2] = fmaf(cf, lo.z, ag[2]); ag[3] = fmaf(cf, lo.w, ag[3]);
        ag[4] = fmaf(cf, hi.x, ag[4]); ag[5] = fmaf(cf, hi.y, ag[5]);
        ag[6] = fmaf(cf, hi.z, ag[6]); ag[7] = fmaf(cf, hi.w, ag[7]);
      }
      const float dv = sm.diss[v];
      const float invd = 1.0f / sm.degs[v];
      float part = 0.0f;
#pragma unroll
      for (int j = 0; j < 8; j++) {
        acc[i][j] = fmaxf(fmaf(ag[j], dv, fmaf(acc[i][j], invd, bv[j])), 0.0f);
        part = fmaf(acc[i][j], wv[j], part);
      }
      atomicAdd(&sm.hsv[v], part);
    }
  }
  __syncthreads();                 // all h reads + hsv atomics done

  // ---- write x1 to xbuf; edge-parallel score atomics ----
#pragma unroll
  for (int i = 0; i < NPT; i++) {
    const int v = lane + (i << 6);
    *xvec(sm.xbuf, v, c4b)     = make_float4(acc[i][0], acc[i][1], acc[i][2], acc[i][3]);
    *xvec(sm.xbuf, v, c4b + 1) = make_float4(acc[i][4], acc[i][5], acc[i][6], acc[i][7]);
  }
  for (int e = tid; e < EDGES; e += NT) {
    const unsigned short r = sm.rc[e];
    if (FIRST || r != SENT) {
      const int row = r >> 8, col = r & 255;
      atomicAdd(&sm.scorev[col], sm.diss[row] * sm.ewl[e] * sm.hsv[row]);
    }
  }
  __syncthreads();
  if (tid < NN) {
    sm.scorev[tid] = sm.scorev[tid] * sm.diss[tid] + sm.hsv[tid] / sm.degs[tid] + bp[0];
    sm.csr_cnt[tid] = 0;
  }
  __syncthreads();

  // ---- parallel exact top-k rank (desc, ties -> lower index) ----
  {
    const int node = tid & (NN - 1);
    const int seg  = tid >> LOG;
    const float sv = sm.scorev[node];
    int part = 0;
    const int u0 = seg * LEN;
#pragma unroll 4
    for (int u = u0; u < u0 + LEN; u++) {
      const float su = sm.scorev[u];
      part += (su > sv) || (su == sv && u < node);
    }
    if (part) atomicAdd(&sm.csr_cnt[node], part);
  }
  __syncthreads();
  if (tid < NN) {
    const int rank = sm.csr_cnt[tid];
    if (rank < K) { sm.perm[rank] = (short)tid; sm.vals[rank] = sm.scorev[tid]; sm.newid[tid] = (signed char)rank; }
    else sm.newid[tid] = -1;
    if (tid < K) { sm.degs[tid] = 1.0f; sm.csr_cnt[tid] = 0; }   // init next stage
  }
  __syncthreads();

  // ---- pool: x_new[i] = x[perm[i]] * tanh(vals[i]) (in-place via regs) ----
  {
    constexpr int TPR = NT / K;          // threads per dest row
    constexpr int C4  = 32 / TPR;        // float4 chunks per thread
    const int drow = tid / TPR;
    const int cc   = (tid % TPR) * C4;
    const int src  = sm.perm[drow];
    const float g  = tanhf(sm.vals[drow]);
    float4 tmp[C4];
#pragma unroll
    for (int j = 0; j < C4; j++) tmp[j] = *xvec(sm.xbuf, src, cc + j);
    __syncthreads();
#pragma unroll
    for (int j = 0; j < C4; j++) {
      tmp[j].x *= g; tmp[j].y *= g; tmp[j].z *= g; tmp[j].w *= g;
      *xvec(sm.xbuf, drow, cc + j) = tmp[j];
    }
  }
  __syncthreads();

  // ---- readout (registers only) + edge remap (+ next deg/count accum) ----
  if (tid < 128) {
    float mx = -INFINITY, sv = 0.0f;
    for (int i = 0; i < K; i++) {
      const float v = sm.xbuf[xidx(i, tid)];
      mx = fmaxf(mx, v); sv += v;
    }
    lmax = mx;
    lmean = sv * (1.0f / K);
  }
  if (REMAP) {
    for (int e = tid; e < EDGES; e += NT) {
      const unsigned short r = sm.rc[e];
      if (FIRST || r != SENT) {
        const int r2 = sm.newid[r >> 8];
        const int c2 = sm.newid[r & 255];
        if (r2 < 0 || c2 < 0) sm.rc[e] = SENT;
        else {
          sm.rc[e] = (unsigned short)((r2 << 8) | c2);
          atomicAdd(&sm.degs[c2], sm.ewl[e]);
          atomicAdd(&sm.csr_cnt[c2], 1);
        }
      }
    }
  }
  __syncthreads();
}

// blocks 0..255: subgraph pipeline + leaf hG
// block 256: independent global-graph prep (degG/CSR/zero) — NO waiting
__global__ __launch_bounds__(NT)
void stageA_kernel(const float* __restrict__ x0,
                   const int* __restrict__ ei, const float* __restrict__ ew,
                   const int* __restrict__ gei,
                   const float* __restrict__ W1, const float* __restrict__ b1,
                   const float* __restrict__ Wp1, const float* __restrict__ bp1,
                   const float* __restrict__ W2, const float* __restrict__ b2,
                   const float* __restrict__ Wp2, const float* __restrict__ bp2,
                   const float* __restrict__ W3, const float* __restrict__ b3,
                   const float* __restrict__ Wp3, const float* __restrict__ bp3,
                   const float* __restrict__ Wg, float* __restrict__ hG,
                   float* __restrict__ degG, int* __restrict__ goff,
                   int* __restrict__ gcsr_row, float* __restrict__ gcsr_coef,
                   float* __restrict__ lacc, int* __restrict__ lctr)
{
  __shared__ SmemA sm;
  const int c = blockIdx.x;
  const int tid = threadIdx.x;

  if (c == 256) {
    // ---- global-graph prep (independent of subgraph results) ----
    int* cnt = (int*)sm.xbuf;          // 320
    int* off = cnt + 320;              // 321
    int* fc  = off + 321;              // 288
    for (int i = tid; i < 320; i += NT) cnt[i] = 0;
    if (tid < 288) fc[tid] = 0;
    __syncthreads();
    for (int e = tid; e < 8192; e += NT) atomicAdd(&cnt[gei[8192 + e]], 1);
    __syncthreads();
    if (tid < 64) {                     // one-wave scan over 320 (Q=5)
      int cc[5], pre[5];
      int tot = 0;
#pragma unroll
      for (int i = 0; i < 5; i++) { cc[i] = cnt[tid * 5 + i]; pre[i] = tot; tot += cc[i]; }
      int inc = tot;
#pragma unroll
      for (int d = 1; d < 64; d <<= 1) {
        const int o = __shfl_up(inc, d, 64);
        if (tid >= d) inc += o;
      }
      const int base = inc - tot;
      if (tid == 0) off[0] = 0;
#pragma unroll
      for (int i = 0; i < 5; i++) off[tid * 5 + i + 1] = base + pre[i] + cc[i];
    }
    if (tid < 273) degG[tid] = 1.0f + (float)cnt[tid];
    __syncthreads();
    for (int e = tid; e < 8192; e += NT) {
      const int col = gei[8192 + e], row = gei[e];
      const int p = atomicAdd(&fc[col], 1);
      const int s = off[col] + p;
      gcsr_row[s]  = row;
      gcsr_coef[s] = rsqrtf(1.0f + (float)cnt[row]);
    }
    if (tid < 274) goff[tid] = off[tid];
    if (tid == 0) { *lacc = 0.0f; *lctr = 0; }
    return;
  }

  if (c == 0 && tid < 256) hG[(size_t)272 * 256 + tid] = 0.0f;   // root hG accum
  const int* eic = ei + (size_t)c * 2 * EDGES;
  const float* ewc = ew + (size_t)c * EDGES;
  const float* xgc = x0 + (size_t)c * 256 * 128;
  float l0 = 0.f, l1 = 0.f, l2 = 0.f, l3 = 0.f, l4 = 0.f, l5 = 0.f;
  run_stage<256, 128, true,  true >(sm, xgc, eic, ewc, W1, b1, Wp1, bp1, l0, l1);
  run_stage<128,  64, false, true >(sm, nullptr, nullptr, nullptr, W2, b2, Wp2, bp2, l2, l3);
  run_stage< 64,  32, false, false>(sm, nullptr, nullptr, nullptr, W3, b3, Wp3, bp3, l4, l5);

  // ---- fused leaf hG row: hG[c] = leaf(768) @ Wg(768x256) ----
  float* leafbuf = sm.csr_coef;   // dead after stage-3
  float* hGacc   = sm.degs;       // dead after stage-3
  if (tid < 256) {
    if (tid < 128) {
      leafbuf[tid]       = l0; leafbuf[128 + tid] = l1;
      leafbuf[256 + tid] = l2; leafbuf[384 + tid] = l3;
      leafbuf[512 + tid] = l4; leafbuf[640 + tid] = l5;
    }
    hGacc[tid] = 0.0f;
  }
  __syncthreads();
  {
    const int f = tid & 255, q = tid >> 8;       // 4 k-quarters x 192
    const float* wgq = Wg + (size_t)(q * 192) * 256 + f;
    const float* lb  = leafbuf + q * 192;
    float p0 = 0.f, p1 = 0.f, p2 = 0.f, p3 = 0.f;
    for (int i = 0; i < 192; i += 4) {
      p0 = fmaf(lb[i],     wgq[(size_t)i * 256],       p0);
      p1 = fmaf(lb[i + 1], wgq[(size_t)(i + 1) * 256], p1);
      p2 = fmaf(lb[i + 2], wgq[(size_t)(i + 2) * 256], p2);
      p3 = fmaf(lb[i + 3], wgq[(size_t)(i + 3) * 256], p3);
    }
    atomicAdd(&hGacc[f], (p0 + p1) + (p2 + p3));
  }
  __syncthreads();
  if (tid < 256) hG[(size_t)c * 256 + tid] = hGacc[tid];
}

// ---------------- global stage ----------------
// 16 blocks: parent p from leaf hG means (+ 1/16 into root row, linearity)
__global__ __launch_bounds__(NT)
void prep_k(float* __restrict__ hG) {
  __shared__ float pr[1024];
  const int tid = threadIdx.x;
  const int p = blockIdx.x;
  const int f = tid & 255, q = tid >> 8;
  float s = 0.f;
  for (int b2 = q; b2 < 16; b2 += 4) s += hG[(size_t)(p * 16 + b2) * 256 + f];
  pr[tid] = s;
  __syncthreads();
  if (tid < 256) {
    const float sv = (pr[tid] + pr[256 + tid] + pr[512 + tid] + pr[768 + tid]) * (1.0f / 16.0f);
    hG[(size_t)(256 + p) * 256 + tid] = sv;
    atomicAdd(&hG[(size_t)272 * 256 + tid], sv * (1.0f / 16.0f));
  }
}

// fused: gx row v (GCN+ReLU via global CSR) -> ce -> A/B link embeddings
__global__ __launch_bounds__(NT)
void gaggemb_k(const float* __restrict__ hG, const float* __restrict__ degG,
               const int* __restrict__ goff, const int* __restrict__ gcsr_row,
               const float* __restrict__ gcsr_coef, const float* __restrict__ bg,
               const float* __restrict__ Wl1, const float* __restrict__ bl1,
               const float* __restrict__ Wl2, const float* __restrict__ bl2,
               float* __restrict__ out_ce, float* __restrict__ A,
               float* __restrict__ B) {
  __shared__ float pacc[1024];
  __shared__ float pacc2[1024];
  __shared__ float gxr[256];
  const int v = blockIdx.x, tid = threadIdx.x;
  const int f = tid & 255, q = tid >> 8;
  {
    const int beg = goff[v], end = goff[v + 1];
    float s = 0.f;
    for (int i = beg + q; i < end; i += 4)
      s = fmaf(gcsr_coef[i], hG[(size_t)gcsr_row[i] * 256 + f], s);
    pacc[tid] = s;
  }
  __syncthreads();
  if (tid < 256) {
    const float dg = degG[v];
    float val = (pacc[tid] + pacc[256 + tid] + pacc[512 + tid] + pacc[768 + tid]) * rsqrtf(dg)
              + hG[(size_t)v * 256 + tid] / dg + bg[tid];
    val = fmaxf(val, 0.0f);
    gxr[tid] = val;
    if (v < 256) out_ce[(size_t)v * 256 + tid] = val;
  }
  __syncthreads();
  {
    const int k0 = q << 6;
    float a = 0.f, b2 = 0.f;
    for (int k = k0; k < k0 + 64; k++) {
      const float g = gxr[k];
      a  = fmaf(g, Wl1[(size_t)k * 256 + f], a);
      b2 = fmaf(g, Wl2[(size_t)k * 256 + f], b2);
    }
    pacc[tid] = a; pacc2[tid] = b2;
  }
  __syncthreads();
  if (tid < 256) {
    A[(size_t)v * 256 + tid] = pacc[tid] + pacc[256 + tid] + pacc[512 + tid] + pacc[768 + tid] + bl1[tid];
    B[(size_t)v * 256 + tid] = pacc2[tid] + pacc2[256 + tid] + pacc2[512 + tid] + pacc2[768 + tid] + bl2[tid];
  }
}

// loss + non-blocking finalize (last-arriving block writes out[65536])
__global__ __launch_bounds__(256)
void loss_k(const float* __restrict__ A, const float* __restrict__ B,
            const int* __restrict__ gei, const int* __restrict__ nei,
            float* __restrict__ acc, int* __restrict__ lctr,
            float* __restrict__ out) {
  const int gw = (blockIdx.x * blockDim.x + threadIdx.x) >> 6;  // 512 waves
  const int lane = threadIdx.x & 63;
  float lsum = 0.0f;
  for (int idx = gw; idx < 16384; idx += 512) {
    const bool ispos = idx < 8192;
    const int e = ispos ? idx : idx - 8192;
    const int* ia = ispos ? gei : nei;
    const int s = ia[e], t = ia[8192 + e];
    float p = 0.0f;
#pragma unroll
    for (int j = 0; j < 4; j++)
      p += A[(size_t)s * 256 + lane + 64 * j] * B[(size_t)t * 256 + lane + 64 * j];
#pragma unroll
    for (int off = 32; off; off >>= 1) p += __shfl_xor(p, off, 64);
    const float z = ispos ? -p : p;
    lsum += fmaxf(z, 0.0f) + log1pf(expf(-fabsf(z)));
  }
  if (lane == 0) atomicAdd(acc, lsum);
  __syncthreads();
  if (threadIdx.x == 0) {
    __threadfence();
    const int old = atomicAdd(lctr, 1);
    if (old == (int)gridDim.x - 1) {
      const float tot = atomicAdd(acc, 0.0f);   // coherent read
      out[65536] = tot * (1.0f / 8192.0f);
    }
  }
}

extern "C" void kernel_launch(void* const* d_in, const int* in_sizes, int n_in,
                              void* d_out, int out_size, void* d_ws, size_t ws_size,
                              hipStream_t stream) {
  const float* x   = (const float*)d_in[0];
  const int*   ei  = (const int*)d_in[1];
  const float* ew  = (const float*)d_in[2];
  const int*   gei = (const int*)d_in[3];
  const int*   nei = (const int*)d_in[4];
  const float* W1  = (const float*)d_in[5];
  const float* b1  = (const float*)d_in[6];
  const float* Wp1 = (const float*)d_in[7];
  const float* bp1 = (const float*)d_in[8];
  const float* W2  = (const float*)d_in[9];
  const float* b2  = (const float*)d_in[10];
  const float* Wp2 = (const float*)d_in[11];
  const float* bp2 = (const float*)d_in[12];
  const float* W3  = (const float*)d_in[13];
  const float* b3  = (const float*)d_in[14];
  const float* Wp3 = (const float*)d_in[15];
  const float* bp3 = (const float*)d_in[16];
  const float* Wg  = (const float*)d_in[17];
  const float* bg  = (const float*)d_in[18];
  const float* Wl1 = (const float*)d_in[19];
  const float* bl1 = (const float*)d_in[20];
  const float* Wl2 = (const float*)d_in[21];
  const float* bl2 = (const float*)d_in[22];

  float* ws       = (float*)d_ws;
  float* hG       = ws;                        // 273*256
  float* degG     = hG + 273 * 256;            // 288 (padded)
  float* Aemb     = degG + 288;                // 273*256
  float* Bemb     = Aemb + 273 * 256;          // 273*256
  float* lacc     = Bemb + 273 * 256;          // 1
  int*   lctr     = (int*)(lacc + 1);          // 1
  int*   goff     = lctr + 1;                  // 288
  int*   gcsr_row = goff + 288;                // 8192
  float* gcsr_coef= (float*)(gcsr_row + 8192); // 8192
  float* out      = (float*)d_out;

  stageA_kernel<<<257, NT, 0, stream>>>(x, ei, ew, gei, W1, b1, Wp1, bp1,
                                        W2, b2, Wp2, bp2, W3, b3, Wp3, bp3,
                                        Wg, hG, degG, goff, gcsr_row, gcsr_coef,
                                        lacc, lctr);
  prep_k<<<16, NT, 0, stream>>>(hG);
  gaggemb_k<<<273, NT, 0, stream>>>(hG, degG, goff, gcsr_row, gcsr_coef, bg,
                                    Wl1, bl1, Wl2, bl2, out, Aemb, Bemb);
  loss_k<<<128, 256, 0, stream>>>(Aemb, Bemb, gei, nei, lacc, lctr, out);
}

// Round 14
// 180.748 us; speedup vs baseline: 1.0420x; 1.0420x over previous
//
#include <hip/hip_runtime.h>
#include <math.h>

#define NT 1024
#define EDGES 2048
#define SENT 0xFFFF

// ---------------- per-subgraph fused pipeline ----------------
struct SmemA {
  float xbuf[256 * 128];           // swizzled node features (128 KB)
  unsigned short rc[EDGES];        // (row<<8)|col ; SENT = dropped
  float ewl[EDGES];                // current edge weights
  unsigned short csr_row[EDGES];   // CSR: source row per slot
  float csr_coef[EDGES];           // CSR: dis[row]*ew per slot (aliased: leafbuf)
  float degs[256];                 // (aliased: hGacc at end)
  float diss[256];
  int   csr_off[257];
  int   csr_cnt[256];              // counts / scan input / rank accumulator
  float hsv[256];                  // score-gcn h
  float scorev[256];
  float vals[128];
  short perm[128];
  signed char newid[256];
};

// xbuf layout: row-major 128 floats/row, float4 chunks XOR-swizzled by row&7.
__device__ __forceinline__ float4* xvec(float* xb, int row, int c4) {
  return reinterpret_cast<float4*>(xb + (row << 7) + ((c4 ^ (row & 7)) << 2));
}
__device__ __forceinline__ int xidx(int row, int col) {
  return (row << 7) + ((((col >> 2) ^ (row & 7)) << 2) | (col & 3));
}

template<int NN, int K, bool FIRST, bool REMAP>
__device__ __forceinline__ void run_stage(
    SmemA& sm,
    const float* __restrict__ xg,        // stage1: global x (else nullptr)
    const int* __restrict__ eic,         // stage1: global edge index
    const float* __restrict__ ewc,       // stage1: global edge weights
    const float* __restrict__ W,         // 128x128 row-major [k][f]
    const float* __restrict__ b,         // 128
    const float* __restrict__ Wp,        // 128
    const float* __restrict__ bp,        // 1
    float& lmax, float& lmean)           // register outputs (tid<128)
{
  constexpr int Q    = NN / 64;          // scan items per lane
  constexpr int SEG  = NT / NN;          // rank segments per node
  constexpr int LEN  = NN / SEG;         // rank items per segment
  constexpr int LOG  = (NN == 256) ? 8 : (NN == 128 ? 7 : 6);
  constexpr int NPT  = (NN == 256) ? 2 : 1;   // rows per lane within row-group
  const int tid  = threadIdx.x;
  const int lane = tid & 63;
  const int wid  = tid >> 6;
  // 8 col-groups x 16 cols, 2 row-groups x NN/2 rows  (halves matmul x-reads)
  const int fbase = __builtin_amdgcn_readfirstlane((wid & 7) << 4);
  const int c4b   = fbase >> 2;                 // chunks c4b..c4b+3
  const int rg    = wid >> 3;
  const int rbase = rg * (NN / 2);
  const bool act  = (NN > 64) || (lane < 32);   // NN==64: lanes 32-63 duplicate
  const int lrow  = (NN == 64) ? (lane & 31) : lane;

  // ---- stage1 only: stage x + edges, build deg/counts ----
  if (FIRST) {
    if (tid < NN) { sm.degs[tid] = 1.0f; sm.csr_cnt[tid] = 0; }
    __syncthreads();
    const float4* xg4 = reinterpret_cast<const float4*>(xg);
    for (int i = tid; i < 256 * 32; i += NT) {
      const float4 v = xg4[i];
      *xvec(sm.xbuf, i >> 5, i & 31) = v;
    }
    for (int e = tid; e < EDGES; e += NT) {
      const int row = eic[e], col = eic[EDGES + e];
      const float w = ewc[e];
      sm.rc[e]  = (unsigned short)((row << 8) | col);
      sm.ewl[e] = w;
      atomicAdd(&sm.degs[col], w);
      atomicAdd(&sm.csr_cnt[col], 1);
    }
    __syncthreads();
  }

  // ---- diss + one-wave shuffle scan of counts -> csr_off ----
  if (tid < NN) sm.diss[tid] = rsqrtf(sm.degs[tid]);
  if (tid < 64) {
    int c[Q], pre[Q];
    int tot = 0;
#pragma unroll
    for (int i = 0; i < Q; i++) { c[i] = sm.csr_cnt[tid * Q + i]; pre[i] = tot; tot += c[i]; }
    int inc = tot;
#pragma unroll
    for (int d = 1; d < 64; d <<= 1) {
      const int o = __shfl_up(inc, d, 64);
      if (tid >= d) inc += o;
    }
    const int base = inc - tot;
    if (tid == 0) sm.csr_off[0] = 0;
#pragma unroll
    for (int i = 0; i < Q; i++) {
      sm.csr_off[tid * Q + i + 1] = base + pre[i] + c[i];
      sm.csr_cnt[tid * Q + i] = 0;
    }
  }
  __syncthreads();

  // ---- CSR fill; zero hsv + scorev here ----
  if (tid < NN) { sm.hsv[tid] = 0.0f; sm.scorev[tid] = 0.0f; }
  for (int e = tid; e < EDGES; e += NT) {
    const unsigned short r = sm.rc[e];
    if (FIRST || r != SENT) {
      const int row = r >> 8, col = r & 255;
      const int p = atomicAdd(&sm.csr_cnt[col], 1);
      const int s = sm.csr_off[col] + p;
      sm.csr_row[s]  = (unsigned short)row;
      sm.csr_coef[s] = sm.diss[row] * sm.ewl[e];
    }
  }
  __syncthreads();

  // ---- matmul: h = x @ W. Wave: 16 cols x (NN/2 rows of its row-group). ----
  float acc[NPT][16];
#pragma unroll
  for (int i = 0; i < NPT; i++)
#pragma unroll
    for (int j = 0; j < 16; j++) acc[i][j] = 0.0f;

#pragma unroll 2
  for (int k4 = 0; k4 < 32; k4++) {
    float4 xv[NPT];
#pragma unroll
    for (int i = 0; i < NPT; i++) xv[i] = *xvec(sm.xbuf, rbase + lrow + (i << 6), k4);
#pragma unroll
    for (int kk = 0; kk < 4; kk++) {
      const float* wr = W + (((k4 << 2) + kk) << 7) + fbase;
      const float4 wa = *reinterpret_cast<const float4*>(wr);
      const float4 wb = *reinterpret_cast<const float4*>(wr + 4);
      const float4 wc = *reinterpret_cast<const float4*>(wr + 8);
      const float4 wd = *reinterpret_cast<const float4*>(wr + 12);
      const float wv[16] = {wa.x, wa.y, wa.z, wa.w, wb.x, wb.y, wb.z, wb.w,
                            wc.x, wc.y, wc.z, wc.w, wd.x, wd.y, wd.z, wd.w};
#pragma unroll
      for (int i = 0; i < NPT; i++) {
        const float xs = (kk == 0) ? xv[i].x : (kk == 1) ? xv[i].y : (kk == 2) ? xv[i].z : xv[i].w;
#pragma unroll
        for (int j = 0; j < 16; j++) acc[i][j] = fmaf(xs, wv[j], acc[i][j]);
      }
    }
  }
  __syncthreads();                 // all x reads done before overwrite

  // ---- write h to xbuf ----
  if (act) {
#pragma unroll
    for (int i = 0; i < NPT; i++) {
      const int v = rbase + lrow + (i << 6);
      *xvec(sm.xbuf, v, c4b)     = make_float4(acc[i][0],  acc[i][1],  acc[i][2],  acc[i][3]);
      *xvec(sm.xbuf, v, c4b + 1) = make_float4(acc[i][4],  acc[i][5],  acc[i][6],  acc[i][7]);
      *xvec(sm.xbuf, v, c4b + 2) = make_float4(acc[i][8],  acc[i][9],  acc[i][10], acc[i][11]);
      *xvec(sm.xbuf, v, c4b + 3) = make_float4(acc[i][12], acc[i][13], acc[i][14], acc[i][15]);
    }
  }
  __syncthreads();

  // ---- agg (depth-1 prefetch) + folded epilogue + hsv partials ----
  {
    const float4 ba = *reinterpret_cast<const float4*>(b + fbase);
    const float4 bb = *reinterpret_cast<const float4*>(b + fbase + 4);
    const float4 bc = *reinterpret_cast<const float4*>(b + fbase + 8);
    const float4 bd = *reinterpret_cast<const float4*>(b + fbase + 12);
    const float bv[16] = {ba.x, ba.y, ba.z, ba.w, bb.x, bb.y, bb.z, bb.w,
                          bc.x, bc.y, bc.z, bc.w, bd.x, bd.y, bd.z, bd.w};
    const float4 wa = *reinterpret_cast<const float4*>(Wp + fbase);
    const float4 wb = *reinterpret_cast<const float4*>(Wp + fbase + 4);
    const float4 wc = *reinterpret_cast<const float4*>(Wp + fbase + 8);
    const float4 wd = *reinterpret_cast<const float4*>(Wp + fbase + 12);
    const float wv[16] = {wa.x, wa.y, wa.z, wa.w, wb.x, wb.y, wb.z, wb.w,
                          wc.x, wc.y, wc.z, wc.w, wd.x, wd.y, wd.z, wd.w};
#pragma unroll
    for (int i = 0; i < NPT; i++) {
      const int v = rbase + lrow + (i << 6);
      const int beg = sm.csr_off[v], end = sm.csr_off[v + 1];
      float ag[16];
#pragma unroll
      for (int j = 0; j < 16; j++) ag[j] = 0.0f;
      float4 p0 = make_float4(0.f,0.f,0.f,0.f), p1 = p0, p2 = p0, p3 = p0;
      float cf_nxt = 0.0f;
      if (beg < end) {
        const int r0 = sm.csr_row[beg];
        cf_nxt = sm.csr_coef[beg];
        p0 = *xvec(sm.xbuf, r0, c4b);     p1 = *xvec(sm.xbuf, r0, c4b + 1);
        p2 = *xvec(sm.xbuf, r0, c4b + 2); p3 = *xvec(sm.xbuf, r0, c4b + 3);
      }
      for (int s = beg; s < end; ++s) {
        const float4 q0 = p0, q1 = p1, q2 = p2, q3 = p3;
        const float cf = cf_nxt;
        if (s + 1 < end) {
          const int rn = sm.csr_row[s + 1];
          cf_nxt = sm.csr_coef[s + 1];
          p0 = *xvec(sm.xbuf, rn, c4b);     p1 = *xvec(sm.xbuf, rn, c4b + 1);
          p2 = *xvec(sm.xbuf, rn, c4b + 2); p3 = *xvec(sm.xbuf, rn, c4b + 3);
        }
        ag[0]  = fmaf(cf, q0.x, ag[0]);  ag[1]  = fmaf(cf, q0.y, ag[1]);
        ag[2]  = fmaf(cf, q0.z, ag[2]);  ag[3]  = fmaf(cf, q0.w, ag[3]);
        ag[4]  = fmaf(cf, q1.x, ag[4]);  ag[5]  = fmaf(cf, q1.y, ag[5]);
        ag[6]  = fmaf(cf, q1.z, ag[6]);  ag[7]  = fmaf(cf, q1.w, ag[7]);
        ag[8]  = fmaf(cf, q2.x, ag[8]);  ag[9]  = fmaf(cf, q2.y, ag[9]);
        ag[10] = fmaf(cf, q2.z, ag[10]); ag[11] = fmaf(cf, q2.w, ag[11]);
        ag[12] = fmaf(cf, q3.x, ag[12]); ag[13] = fmaf(cf, q3.y, ag[13]);
        ag[14] = fmaf(cf, q3.z, ag[14]); ag[15] = fmaf(cf, q3.w, ag[15]);
      }
      const float dv = sm.diss[v];
      const float invd = 1.0f / sm.degs[v];
      float part = 0.0f;
#pragma unroll
      for (int j = 0; j < 16; j++) {
        acc[i][j] = fmaxf(fmaf(ag[j], dv, fmaf(acc[i][j], invd, bv[j])), 0.0f);
        part = fmaf(acc[i][j], wv[j], part);
      }
      if (act) atomicAdd(&sm.hsv[v], part);
    }
  }
  __syncthreads();                 // all h reads + hsv atomics done

  // ---- write x1 to xbuf; edge-parallel score atomics ----
  if (act) {
#pragma unroll
    for (int i = 0; i < NPT; i++) {
      const int v = rbase + lrow + (i << 6);
      *xvec(sm.xbuf, v, c4b)     = make_float4(acc[i][0],  acc[i][1],  acc[i][2],  acc[i][3]);
      *xvec(sm.xbuf, v, c4b + 1) = make_float4(acc[i][4],  acc[i][5],  acc[i][6],  acc[i][7]);
      *xvec(sm.xbuf, v, c4b + 2) = make_float4(acc[i][8],  acc[i][9],  acc[i][10], acc[i][11]);
      *xvec(sm.xbuf, v, c4b + 3) = make_float4(acc[i][12], acc[i][13], acc[i][14], acc[i][15]);
    }
  }
  for (int e = tid; e < EDGES; e += NT) {
    const unsigned short r = sm.rc[e];
    if (FIRST || r != SENT) {
      const int row = r >> 8, col = r & 255;
      atomicAdd(&sm.scorev[col], sm.diss[row] * sm.ewl[e] * sm.hsv[row]);
    }
  }
  __syncthreads();
  if (tid < NN) {
    sm.scorev[tid] = sm.scorev[tid] * sm.diss[tid] + sm.hsv[tid] / sm.degs[tid] + bp[0];
    sm.csr_cnt[tid] = 0;
  }
  __syncthreads();

  // ---- parallel exact top-k rank (desc, ties -> lower index) ----
  {
    const int node = tid & (NN - 1);
    const int seg  = tid >> LOG;
    const float sv = sm.scorev[node];
    int part = 0;
    const int u0 = seg * LEN;
#pragma unroll 4
    for (int u = u0; u < u0 + LEN; u++) {
      const float su = sm.scorev[u];
      part += (su > sv) || (su == sv && u < node);
    }
    if (part) atomicAdd(&sm.csr_cnt[node], part);
  }
  __syncthreads();
  if (tid < NN) {
    const int rank = sm.csr_cnt[tid];
    if (rank < K) { sm.perm[rank] = (short)tid; sm.vals[rank] = sm.scorev[tid]; sm.newid[tid] = (signed char)rank; }
    else sm.newid[tid] = -1;
    if (tid < K) { sm.degs[tid] = 1.0f; sm.csr_cnt[tid] = 0; }   // init next stage
  }
  __syncthreads();

  // ---- pool: x_new[i] = x[perm[i]] * tanh(vals[i]) (in-place via regs) ----
  {
    constexpr int TPR = NT / K;          // threads per dest row
    constexpr int C4  = 32 / TPR;        // float4 chunks per thread
    const int drow = tid / TPR;
    const int cc   = (tid % TPR) * C4;
    const int src  = sm.perm[drow];
    const float g  = tanhf(sm.vals[drow]);
    float4 tmp[C4];
#pragma unroll
    for (int j = 0; j < C4; j++) tmp[j] = *xvec(sm.xbuf, src, cc + j);
    __syncthreads();
#pragma unroll
    for (int j = 0; j < C4; j++) {
      tmp[j].x *= g; tmp[j].y *= g; tmp[j].z *= g; tmp[j].w *= g;
      *xvec(sm.xbuf, drow, cc + j) = tmp[j];
    }
  }
  __syncthreads();

  // ---- readout (registers only) + edge remap (+ next deg/count accum) ----
  if (tid < 128) {
    float mx = -INFINITY, sv = 0.0f;
    for (int i = 0; i < K; i++) {
      const float v = sm.xbuf[xidx(i, tid)];
      mx = fmaxf(mx, v); sv += v;
    }
    lmax = mx;
    lmean = sv * (1.0f / K);
  }
  if (REMAP) {
    for (int e = tid; e < EDGES; e += NT) {
      const unsigned short r = sm.rc[e];
      if (FIRST || r != SENT) {
        const int r2 = sm.newid[r >> 8];
        const int c2 = sm.newid[r & 255];
        if (r2 < 0 || c2 < 0) sm.rc[e] = SENT;
        else {
          sm.rc[e] = (unsigned short)((r2 << 8) | c2);
          atomicAdd(&sm.degs[c2], sm.ewl[e]);
          atomicAdd(&sm.csr_cnt[c2], 1);
        }
      }
    }
  }
  __syncthreads();
}

// blocks 0..255: subgraph pipeline + leaf hG
// block 256: independent global-graph prep (degG/CSR/zero) — NO waiting
__global__ __launch_bounds__(NT)
void stageA_kernel(const float* __restrict__ x0,
                   const int* __restrict__ ei, const float* __restrict__ ew,
                   const int* __restrict__ gei,
                   const float* __restrict__ W1, const float* __restrict__ b1,
                   const float* __restrict__ Wp1, const float* __restrict__ bp1,
                   const float* __restrict__ W2, const float* __restrict__ b2,
                   const float* __restrict__ Wp2, const float* __restrict__ bp2,
                   const float* __restrict__ W3, const float* __restrict__ b3,
                   const float* __restrict__ Wp3, const float* __restrict__ bp3,
                   const float* __restrict__ Wg, float* __restrict__ hG,
                   float* __restrict__ degG, int* __restrict__ goff,
                   int* __restrict__ gcsr_row, float* __restrict__ gcsr_coef,
                   float* __restrict__ lacc, int* __restrict__ lctr)
{
  __shared__ SmemA sm;
  const int c = blockIdx.x;
  const int tid = threadIdx.x;

  if (c == 256) {
    // ---- global-graph prep (independent of subgraph results) ----
    int* cnt = (int*)sm.xbuf;          // 320
    int* off = cnt + 320;              // 321
    int* fc  = off + 321;              // 288
    for (int i = tid; i < 320; i += NT) cnt[i] = 0;
    if (tid < 288) fc[tid] = 0;
    __syncthreads();
    for (int e = tid; e < 8192; e += NT) atomicAdd(&cnt[gei[8192 + e]], 1);
    __syncthreads();
    if (tid < 64) {                     // one-wave scan over 320 (Q=5)
      int cc[5], pre[5];
      int tot = 0;
#pragma unroll
      for (int i = 0; i < 5; i++) { cc[i] = cnt[tid * 5 + i]; pre[i] = tot; tot += cc[i]; }
      int inc = tot;
#pragma unroll
      for (int d = 1; d < 64; d <<= 1) {
        const int o = __shfl_up(inc, d, 64);
        if (tid >= d) inc += o;
      }
      const int base = inc - tot;
      if (tid == 0) off[0] = 0;
#pragma unroll
      for (int i = 0; i < 5; i++) off[tid * 5 + i + 1] = base + pre[i] + cc[i];
    }
    if (tid < 273) degG[tid] = 1.0f + (float)cnt[tid];
    __syncthreads();
    for (int e = tid; e < 8192; e += NT) {
      const int col = gei[8192 + e], row = gei[e];
      const int p = atomicAdd(&fc[col], 1);
      const int s = off[col] + p;
      gcsr_row[s]  = row;
      gcsr_coef[s] = rsqrtf(1.0f + (float)cnt[row]);
    }
    if (tid < 274) goff[tid] = off[tid];
    if (tid == 0) { *lacc = 0.0f; *lctr = 0; }
    return;
  }

  if (c == 0 && tid < 256) hG[(size_t)272 * 256 + tid] = 0.0f;   // root hG accum
  const int* eic = ei + (size_t)c * 2 * EDGES;
  const float* ewc = ew + (size_t)c * EDGES;
  const float* xgc = x0 + (size_t)c * 256 * 128;
  float l0 = 0.f, l1 = 0.f, l2 = 0.f, l3 = 0.f, l4 = 0.f, l5 = 0.f;
  run_stage<256, 128, true,  true >(sm, xgc, eic, ewc, W1, b1, Wp1, bp1, l0, l1);
  run_stage<128,  64, false, true >(sm, nullptr, nullptr, nullptr, W2, b2, Wp2, bp2, l2, l3);
  run_stage< 64,  32, false, false>(sm, nullptr, nullptr, nullptr, W3, b3, Wp3, bp3, l4, l5);

  // ---- fused leaf hG row: hG[c] = leaf(768) @ Wg(768x256) ----
  float* leafbuf = sm.csr_coef;   // dead after stage-3
  float* hGacc   = sm.degs;       // dead after stage-3
  if (tid < 256) {
    if (tid < 128) {
      leafbuf[tid]       = l0; leafbuf[128 + tid] = l1;
      leafbuf[256 + tid] = l2; leafbuf[384 + tid] = l3;
      leafbuf[512 + tid] = l4; leafbuf[640 + tid] = l5;
    }
    hGacc[tid] = 0.0f;
  }
  __syncthreads();
  {
    const int f = tid & 255, q = tid >> 8;       // 4 k-quarters x 192
    const float* wgq = Wg + (size_t)(q * 192) * 256 + f;
    const float* lb  = leafbuf + q * 192;
    float p0 = 0.f, p1 = 0.f, p2 = 0.f, p3 = 0.f;
    for (int i = 0; i < 192; i += 4) {
      p0 = fmaf(lb[i],     wgq[(size_t)i * 256],       p0);
      p1 = fmaf(lb[i + 1], wgq[(size_t)(i + 1) * 256], p1);
      p2 = fmaf(lb[i + 2], wgq[(size_t)(i + 2) * 256], p2);
      p3 = fmaf(lb[i + 3], wgq[(size_t)(i + 3) * 256], p3);
    }
    atomicAdd(&hGacc[f], (p0 + p1) + (p2 + p3));
  }
  __syncthreads();
  if (tid < 256) hG[(size_t)c * 256 + tid] = hGacc[tid];
}

// ---------------- global stage ----------------
// 16 blocks: parent p from leaf hG means (+ 1/16 into root row, linearity)
__global__ __launch_bounds__(NT)
void prep_k(float* __restrict__ hG) {
  __shared__ float pr[1024];
  const int tid = threadIdx.x;
  const int p = blockIdx.x;
  const int f = tid & 255, q = tid >> 8;
  float s = 0.f;
  for (int b2 = q; b2 < 16; b2 += 4) s += hG[(size_t)(p * 16 + b2) * 256 + f];
  pr[tid] = s;
  __syncthreads();
  if (tid < 256) {
    const float sv = (pr[tid] + pr[256 + tid] + pr[512 + tid] + pr[768 + tid]) * (1.0f / 16.0f);
    hG[(size_t)(256 + p) * 256 + tid] = sv;
    atomicAdd(&hG[(size_t)272 * 256 + tid], sv * (1.0f / 16.0f));
  }
}

// fused: gx row v (GCN+ReLU via global CSR) -> ce -> A/B link embeddings
__global__ __launch_bounds__(NT)
void gaggemb_k(const float* __restrict__ hG, const float* __restrict__ degG,
               const int* __restrict__ goff, const int* __restrict__ gcsr_row,
               const float* __restrict__ gcsr_coef, const float* __restrict__ bg,
               const float* __restrict__ Wl1, const float* __restrict__ bl1,
               const float* __restrict__ Wl2, const float* __restrict__ bl2,
               float* __restrict__ out_ce, float* __restrict__ A,
               float* __restrict__ B) {
  __shared__ float pacc[1024];
  __shared__ float pacc2[1024];
  __shared__ float gxr[256];
  const int v = blockIdx.x, tid = threadIdx.x;
  const int f = tid & 255, q = tid >> 8;
  {
    const int beg = goff[v], end = goff[v + 1];
    float s = 0.f;
    for (int i = beg + q; i < end; i += 4)
      s = fmaf(gcsr_coef[i], hG[(size_t)gcsr_row[i] * 256 + f], s);
    pacc[tid] = s;
  }
  __syncthreads();
  if (tid < 256) {
    const float dg = degG[v];
    float val = (pacc[tid] + pacc[256 + tid] + pacc[512 + tid] + pacc[768 + tid]) * rsqrtf(dg)
              + hG[(size_t)v * 256 + tid] / dg + bg[tid];
    val = fmaxf(val, 0.0f);
    gxr[tid] = val;
    if (v < 256) out_ce[(size_t)v * 256 + tid] = val;
  }
  __syncthreads();
  {
    const int k0 = q << 6;
    float a = 0.f, b2 = 0.f;
    for (int k = k0; k < k0 + 64; k++) {
      const float g = gxr[k];
      a  = fmaf(g, Wl1[(size_t)k * 256 + f], a);
      b2 = fmaf(g, Wl2[(size_t)k * 256 + f], b2);
    }
    pacc[tid] = a; pacc2[tid] = b2;
  }
  __syncthreads();
  if (tid < 256) {
    A[(size_t)v * 256 + tid] = pacc[tid] + pacc[256 + tid] + pacc[512 + tid] + pacc[768 + tid] + bl1[tid];
    B[(size_t)v * 256 + tid] = pacc2[tid] + pacc2[256 + tid] + pacc2[512 + tid] + pacc2[768 + tid] + bl2[tid];
  }
}

// loss + non-blocking finalize (last-arriving block writes out[65536])
__global__ __launch_bounds__(256)
void loss_k(const float* __restrict__ A, const float* __restrict__ B,
            const int* __restrict__ gei, const int* __restrict__ nei,
            float* __restrict__ acc, int* __restrict__ lctr,
            float* __restrict__ out) {
  const int gw = (blockIdx.x * blockDim.x + threadIdx.x) >> 6;  // 512 waves
  const int lane = threadIdx.x & 63;
  float lsum = 0.0f;
  for (int idx = gw; idx < 16384; idx += 512) {
    const bool ispos = idx < 8192;
    const int e = ispos ? idx : idx - 8192;
    const int* ia = ispos ? gei : nei;
    const int s = ia[e], t = ia[8192 + e];
    float p = 0.0f;
#pragma unroll
    for (int j = 0; j < 4; j++)
      p += A[(size_t)s * 256 + lane + 64 * j] * B[(size_t)t * 256 + lane + 64 * j];
#pragma unroll
    for (int off = 32; off; off >>= 1) p += __shfl_xor(p, off, 64);
    const float z = ispos ? -p : p;
    lsum += fmaxf(z, 0.0f) + log1pf(expf(-fabsf(z)));
  }
  if (lane == 0) atomicAdd(acc, lsum);
  __syncthreads();
  if (threadIdx.x == 0) {
    __threadfence();
    const int old = atomicAdd(lctr, 1);
    if (old == (int)gridDim.x - 1) {
      const float tot = atomicAdd(acc, 0.0f);   // coherent read
      out[65536] = tot * (1.0f / 8192.0f);
    }
  }
}

extern "C" void kernel_launch(void* const* d_in, const int* in_sizes, int n_in,
                              void* d_out, int out_size, void* d_ws, size_t ws_size,
                              hipStream_t stream) {
  const float* x   = (const float*)d_in[0];
  const int*   ei  = (const int*)d_in[1];
  const float* ew  = (const float*)d_in[2];
  const int*   gei = (const int*)d_in[3];
  const int*   nei = (const int*)d_in[4];
  const float* W1  = (const float*)d_in[5];
  const float* b1  = (const float*)d_in[6];
  const float* Wp1 = (const float*)d_in[7];
  const float* bp1 = (const float*)d_in[8];
  const float* W2  = (const float*)d_in[9];
  const float* b2  = (const float*)d_in[10];
  const float* Wp2 = (const float*)d_in[11];
  const float* bp2 = (const float*)d_in[12];
  const float* W3  = (const float*)d_in[13];
  const float* b3  = (const float*)d_in[14];
  const float* Wp3 = (const float*)d_in[15];
  const float* bp3 = (const float*)d_in[16];
  const float* Wg  = (const float*)d_in[17];
  const float* bg  = (const float*)d_in[18];
  const float* Wl1 = (const float*)d_in[19];
  const float* bl1 = (const float*)d_in[20];
  const float* Wl2 = (const float*)d_in[21];
  const float* bl2 = (const float*)d_in[22];

  float* ws       = (float*)d_ws;
  float* hG       = ws;                        // 273*256
  float* degG     = hG + 273 * 256;            // 288 (padded)
  float* Aemb     = degG + 288;                // 273*256
  float* Bemb     = Aemb + 273 * 256;          // 273*256
  float* lacc     = Bemb + 273 * 256;          // 1
  int*   lctr     = (int*)(lacc + 1);          // 1
  int*   goff     = lctr + 1;                  // 288
  int*   gcsr_row = goff + 288;                // 8192
  float* gcsr_coef= (float*)(gcsr_row + 8192); // 8192
  float* out      = (float*)d_out;

  stageA_kernel<<<257, NT, 0, stream>>>(x, ei, ew, gei, W1, b1, Wp1, bp1,
                                        W2, b2, Wp2, bp2, W3, b3, Wp3, bp3,
                                        Wg, hG, degG, goff, gcsr_row, gcsr_coef,
                                        lacc, lctr);
  prep_k<<<16, NT, 0, stream>>>(hG);
  gaggemb_k<<<273, NT, 0, stream>>>(hG, degG, goff, gcsr_row, gcsr_coef, bg,
                                    Wl1, bl1, Wl2, bl2, out, Aemb, Bemb);
  loss_k<<<128, 256, 0, stream>>>(Aemb, Bemb, gei, nei, lacc, lctr, out);
}